// Round 1
// baseline (1736.075 us; speedup 1.0000x reference)
//
#include <hip/hip_runtime.h>

#define ROWLEN 32768
#define TOPK   32
#define CAP    2048
#define BLOCK  256
#define NITER  (ROWLEN / 4 / BLOCK)   // 32 float4 loads per thread
#define THRESH 2.5f

typedef float f4 __attribute__((ext_vector_type(4)));

// One block per row. Fused: stream row in, zero the output row, collect
// candidates (> THRESH) into LDS, exact rank-select top-32, scatter ReLU'd
// values. Fallback path (never taken for N(0,1) rows) does an exact
// bit-level threshold binary search with count-only passes.
__global__ __launch_bounds__(BLOCK, 4)
void topk_609885356663(const float* __restrict__ x, float* __restrict__ out) {
    __shared__ unsigned long long s_keys[CAP];
    __shared__ int s_cnt;
    __shared__ int s_above;

    const int row = blockIdx.x;
    const int tid = threadIdx.x;
    const f4* __restrict__ xrow4 = (const f4*)(x + (size_t)row * ROWLEN);
    f4* __restrict__ orow4 = (f4*)(out + (size_t)row * ROWLEN);
    float* __restrict__ orow = out + (size_t)row * ROWLEN;

    if (tid == 0) s_cnt = 0;
    __syncthreads();

    const f4 z4 = {0.f, 0.f, 0.f, 0.f};
#pragma unroll 4
    for (int i = 0; i < NITER; ++i) {
        const int vi = i * BLOCK + tid;
        f4 v = xrow4[vi];
        orow4[vi] = z4;
        float mx = fmaxf(fmaxf(v[0], v[1]), fmaxf(v[2], v[3]));
        if (mx > THRESH) {
            const int base = vi * 4;
#pragma unroll
            for (int c = 0; c < 4; ++c) {
                float f = v[c];
                if (f > THRESH) {
                    int p = atomicAdd(&s_cnt, 1);
                    if (p < CAP) {
                        unsigned long long key =
                            ((unsigned long long)__float_as_uint(f) << 32) |
                            (unsigned int)(~(unsigned int)(base + c));
                        s_keys[p] = key;
                    }
                }
            }
        }
    }
    __syncthreads();

    const int cnt = s_cnt;
    if (cnt >= TOPK && cnt <= CAP) {
        // Exact rank select: candidate keys are strictly distinct (idx part),
        // so exactly TOPK keys have rank < TOPK. LDS reads are broadcast
        // (all lanes read same address) -> conflict-free.
        for (int t = tid; t < cnt; t += BLOCK) {
            const unsigned long long my = s_keys[t];
            int rank = 0;
            for (int j = 0; j < cnt; ++j) {
                rank += (s_keys[j] > my) ? 1 : 0;
            }
            if (rank < TOPK) {
                unsigned int idx = ~(unsigned int)(my & 0xFFFFFFFFull);
                float val = __uint_as_float((unsigned int)(my >> 32));
                orow[idx] = fmaxf(val, 0.f);  // val > THRESH > 0; relu is a no-op
            }
        }
        return;
    }

    // ---------------- Fallback (rare / pathological rows) ----------------
    // Only positive values matter: relu(v<=0)=0 == background. Map
    // u(v) = v>0 ? bits(v) : 0 (monotone for positives). Binary search the
    // smallest t with count(u > t) < TOPK.
    unsigned int lo = 0u, hi = 0x7F800000u;  // count(u > inf_bits) == 0 < TOPK
    while (lo < hi) {
        const unsigned int mid = lo + (hi - lo) / 2u;
        if (tid == 0) s_cnt = 0;
        __syncthreads();
        int local = 0;
        for (int i = 0; i < NITER; ++i) {
            const int vi = i * BLOCK + tid;
            f4 v = xrow4[vi];
#pragma unroll
            for (int c = 0; c < 4; ++c) {
                const float f = v[c];
                const unsigned int u = (f > 0.f) ? __float_as_uint(f) : 0u;
                local += (u > mid) ? 1 : 0;
            }
        }
        atomicAdd(&s_cnt, local);
        __syncthreads();
        const int c = s_cnt;
        __syncthreads();  // everyone reads c before next-iteration reset
        if (c < TOPK) hi = mid; else lo = mid + 1u;
    }
    const unsigned int tstar = lo;

    // Collect: u > tstar -> definitely selected (count < TOPK), write now.
    // u == tstar (and tstar != 0) -> tie candidates, resolved by index.
    if (tid == 0) { s_cnt = 0; s_above = 0; }
    __syncthreads();
    for (int i = 0; i < NITER; ++i) {
        const int vi = i * BLOCK + tid;
        f4 v = xrow4[vi];
#pragma unroll
        for (int c = 0; c < 4; ++c) {
            const float f = v[c];
            const unsigned int u = (f > 0.f) ? __float_as_uint(f) : 0u;
            const int idx = vi * 4 + c;
            if (u > tstar) {
                atomicAdd(&s_above, 1);
                orow[idx] = f;  // u > tstar >= 0 implies f > 0
            } else if (u == tstar && tstar != 0u) {
                int p = atomicAdd(&s_cnt, 1);
                if (p < CAP) s_keys[p] = (unsigned long long)(unsigned int)idx;
            }
        }
    }
    __syncthreads();

    const int A = s_above;           // strictly < TOPK by construction
    const int R = TOPK - A;          // slots left for ties (>= 1 if tstar != 0)
    const int tcnt = min(s_cnt, CAP);
    if (tstar != 0u && R > 0) {
        const float tval = __uint_as_float(tstar);  // > 0
        for (int t = tid; t < tcnt; t += BLOCK) {
            const unsigned long long my = s_keys[t];
            int rank = 0;
            for (int j = 0; j < tcnt; ++j) {
                rank += (s_keys[j] < my) ? 1 : 0;  // smaller index first
            }
            if (rank < R) {
                orow[(unsigned int)my] = tval;
            }
        }
    }
}

extern "C" void kernel_launch(void* const* d_in, const int* in_sizes, int n_in,
                              void* d_out, int out_size, void* d_ws, size_t ws_size,
                              hipStream_t stream) {
    const float* x = (const float*)d_in[0];
    float* out = (float*)d_out;
    const int nrows = in_sizes[0] / ROWLEN;  // 8192
    topk_609885356663<<<nrows, BLOCK, 0, stream>>>(x, out);
}